// Round 15
// baseline (151.461 us; speedup 1.0000x reference)
//
#include <hip/hip_runtime.h>

#define B_ 8
#define C_ 512
#define N_ 2304
#define CQ 64

typedef float f32x4 __attribute__((ext_vector_type(4)));
typedef float f32x16 __attribute__((ext_vector_type(16)));
typedef short bf16x8 __attribute__((ext_vector_type(8)));
typedef unsigned short u16x4 __attribute__((ext_vector_type(4)));
typedef unsigned short u16x8 __attribute__((ext_vector_type(8)));
typedef int i32x4 __attribute__((ext_vector_type(4)));

__device__ __forceinline__ unsigned short f2bf(float f){
  union { float f; unsigned int u; } v; v.f = f;
  unsigned int r = (v.u + 0x7fffu + ((v.u >> 16) & 1u)) >> 16;
  return (unsigned short)r;
}

// ---------------- W -> bf16, MFMA-A-frag BLOCKED layout ----------------
__global__ __launch_bounds__(256) void k_wcvt(const float* __restrict__ Wq,
                                              const float* __restrict__ Wk,
                                              const float* __restrict__ Wv,
                                              unsigned short* __restrict__ Wb){
  int idx = blockIdx.x*256 + threadIdx.x;         // 40960 chunks
  int h = idx & 1, ln = (idx >> 1) & 31, cs = (idx >> 6) & 31, ob = idx >> 11;
  int row = ob*32 + ln, col = cs*16 + h*8;
  const float* src;
  if (row < 64)       src = Wq + (size_t)row*512 + col;
  else if (row < 128) src = Wk + (size_t)(row-64)*512 + col;
  else                src = Wv + (size_t)(row-128)*512 + col;
  f32x4 v0 = *(const f32x4*)src;
  f32x4 v1 = *(const f32x4*)(src + 4);
  u16x8 o;
  #pragma unroll
  for (int j = 0; j < 4; j++){ o[j] = f2bf(v0[j]); o[4+j] = f2bf(v1[j]); }
  *(u16x8*)(Wb + (size_t)idx*8) = o;
}

// ---------------- fused prep: transpose + Q/K/V projections ----------------
// V output now in A-frag BLOCKED layout:
// vb chunk (b, mblk 0..143, cg 0..15): 1KB; lane (ln,h) shorts at
//   (((b*144 + mblk)*16 + cg)*512 + (ln*2 + h)*8)
// holding V[cg*32+ln][m-block mblk, perm-slots h*8..h*8+8)  (same q2 perm).
__global__ __launch_bounds__(512) void k_prep(const float* __restrict__ x,
                                              const float* __restrict__ bq,
                                              const float* __restrict__ bk,
                                              const float* __restrict__ bv,
                                              const unsigned short* __restrict__ Wb,
                                              unsigned short* __restrict__ qw,
                                              unsigned short* __restrict__ kw,
                                              unsigned short* __restrict__ vb){
  __shared__ short xt_l[32*520];          // 33.3 KB
  __shared__ float scr[2*32*68];          // 17.4 KB

  int i = blockIdx.x; int b = i & 7; int nt = i >> 3;
  int n0 = nt*32;
  int t = threadIdx.x; int w = t >> 6; int l = t & 63;
  int h = l >> 5, ln = l & 31;
  const size_t bN = (size_t)b*N_;

  // ---- phase 1: stage x -> xt_l ----
  #pragma unroll
  for (int it = 0; it < 8; it++){
    int c = it*64 + (t >> 3);
    int n4 = (t & 7)*4;
    f32x4 v = *(const f32x4*)(x + ((size_t)b*C_ + c)*N_ + n0 + n4);
    #pragma unroll
    for (int j = 0; j < 4; j++) xt_l[(n4+j)*520 + c] = (short)f2bf(v[j]);
  }
  __syncthreads();

  // ---- phase 2: GEMMs ----
  const unsigned short* wlane = Wb + (size_t)(ln*2 + h)*8;
  const unsigned short* wv0 = wlane + (size_t)(4 + 2*w)*16384;
  const unsigned short* wv1 = wlane + (size_t)(5 + 2*w)*16384;
  const unsigned short* wqk = wlane + (size_t)w*16384;

  f32x16 vacc[2]; f32x16 qkacc;
  #pragma unroll
  for (int rr = 0; rr < 16; rr++){ vacc[0][rr]=0.f; vacc[1][rr]=0.f; qkacc[rr]=0.f; }

  #pragma unroll 8
  for (int cs = 0; cs < 32; cs++){
    bf16x8 bx = *(const bf16x8*)&xt_l[ln*520 + cs*16 + h*8];
    bf16x8 a0 = *(const bf16x8*)(wv0 + (size_t)cs*512);
    bf16x8 a1 = *(const bf16x8*)(wv1 + (size_t)cs*512);
    vacc[0] = __builtin_amdgcn_mfma_f32_32x32x16_bf16(a0, bx, vacc[0], 0, 0, 0);
    vacc[1] = __builtin_amdgcn_mfma_f32_32x32x16_bf16(a1, bx, vacc[1], 0, 0, 0);
    if (w < 4){
      bf16x8 aq = *(const bf16x8*)(wqk + (size_t)cs*512);
      qkacc = __builtin_amdgcn_mfma_f32_32x32x16_bf16(aq, bx, qkacc, 0, 0, 0);
    }
  }

  // ---- phase 3a: Q/K scratch + cooperative store ----
  if (w < 4){
    float* s = scr + ((w >> 1) ? 2176 : 0);
    int obase = (w & 1)*32;
    #pragma unroll
    for (int rr = 0; rr < 16; rr++){
      int o = obase + (rr & 3) + 8*(rr >> 2) + 4*h;
      s[ln*68 + o] = qkacc[rr];
    }
  }
  __syncthreads();

  if (t < 256){
    int isK = t >> 7;
    int tt = t & 127;
    int n = tt >> 2, j = tt & 3;
    const float* s = scr + (isK ? 2176 : 0);
    const float* bias = isK ? bk : bq;
    float vals[16]; float sm = 0.f;
    #pragma unroll
    for (int ii = 0; ii < 16; ii++){
      vals[ii] = s[n*68 + j*16 + ii] + bias[j*16 + ii];
      sm += vals[ii];
    }
    sm += __shfl_xor(sm, 1); sm += __shfl_xor(sm, 2);
    float mean = isK ? 0.f : sm * (1.f/64.f);
    float scl  = isK ? 1.f : (1.44269504089f/512.f);
    u16x8 h0, h1;
    #pragma unroll
    for (int ii = 0; ii < 8; ii++) h0[ii] = f2bf((vals[ii]   - mean)*scl);
    #pragma unroll
    for (int ii = 0; ii < 8; ii++) h1[ii] = f2bf((vals[8+ii] - mean)*scl);
    unsigned short* d = (isK ? kw : qw) + (bN + n0 + n)*CQ + j*16;
    *(u16x8*)d = h0;
    *(u16x8*)(d + 8) = h1;
  }
  __syncthreads();

  // ---- phase 3b: V epilogue -> blocked vb, 4 rounds x 2 chunks of 64 o ----
  #pragma unroll
  for (int r = 0; r < 4; r++){
    if ((w >> 1) == r){
      float* s = scr + (w & 1)*2176;
      #pragma unroll
      for (int of = 0; of < 2; of++)
        #pragma unroll
        for (int rr = 0; rr < 16; rr++){
          int o = of*32 + (rr & 3) + 8*(rr >> 2) + 4*h;
          s[ln*68 + o] = vacc[of][rr];
        }
    }
    __syncthreads();
    {
      int ch = t >> 8;
      int tt = t & 255;
      int o = tt >> 2, jj = (tt >> 1) & 1, half = tt & 1;
      int og = (2*r + ch)*64 + o;
      const float* s = scr + ch*2176;
      float bvv = bv[og];
      u16x8 hv;
      #pragma unroll
      for (int ii = 0; ii < 8; ii++){
        int q2 = ((ii & 3) | ((ii & 4) << 1)) + half*4;   // swap bits 2,3 of pos
        hv[ii] = f2bf(s[(jj*16 + q2)*68 + o] + bvv);
      }
      size_t dst = (((size_t)b*144 + 2*nt + jj)*16 + (og >> 5))*512 + (og & 31)*16 + half*8;
      *(u16x8*)(vb + dst) = hv;
    }
    __syncthreads();
  }
}

// ---------------- S + exp2 -> P (blocked frag-ready layout), K-prefetch pipelined ----------------
__global__ __launch_bounds__(256) void k_sexp(const unsigned short* __restrict__ qw,
                                              const unsigned short* __restrict__ kw,
                                              unsigned short* __restrict__ Pl,
                                              float* __restrict__ lsum_part,
                                              int b0, int bsh){
  int bid = blockIdx.x;
  int bl = bid & ((1 << bsh) - 1);
  int b = b0 + bl;
  int r = bid >> bsh;
  int ms = r & 3; int nt = r >> 2;
  int t = threadIdx.x; int w = t >> 6; int l = t & 63;
  int h = l >> 5, ln = l & 31;
  int nf = w & 1, mh = w >> 1;
  int n = nt*64 + nf*32 + ln;

  const unsigned short* qb = qw + ((size_t)b*N_ + n)*CQ + h*8;
  bf16x8 qf[4];
  #pragma unroll
  for (int kq = 0; kq < 4; kq++) qf[kq] = *(const bf16x8*)(qb + kq*16);

  int mb32base = ms*18 + mh*9;
  const unsigned short* ks0 = kw + ((size_t)b*N_ + ln)*CQ + h*8 + (size_t)mb32base*32*CQ;
  unsigned short* pb = Pl + ((size_t)bl*144*N_ + n)*16 + h*8;

  float lsum = 0.f;
  bf16x8 ka[4], kc[4];
  #pragma unroll
  for (int kq = 0; kq < 4; kq++) ka[kq] = *(const bf16x8*)(ks0 + kq*16);

  #define SEXP_BODY(MF, KF, KN, PFOFF)                                          \
  {                                                                             \
    _Pragma("unroll")                                                           \
    for (int kq = 0; kq < 4; kq++)                                              \
      KN[kq] = *(const bf16x8*)(ks0 + (size_t)(PFOFF)*32*CQ + kq*16);           \
    f32x16 sv;                                                                  \
    _Pragma("unroll")                                                           \
    for (int rr = 0; rr < 16; rr++) sv[rr] = 0.f;                               \
    _Pragma("unroll")                                                           \
    for (int kq = 0; kq < 4; kq++)                                              \
      sv = __builtin_amdgcn_mfma_f32_32x32x16_bf16(KF[kq], qf[kq], sv, 0, 0, 0);\
    float e[16];                                                                \
    _Pragma("unroll")                                                           \
    for (int rr = 0; rr < 16; rr++) e[rr] = exp2f(sv[rr]);                      \
    _Pragma("unroll")                                                           \
    for (int rr = 0; rr < 16; rr++) lsum += e[rr];                              \
    unsigned int pd[8];                                                         \
    _Pragma("unroll")                                                           \
    for (int j = 0; j < 8; j++)                                                 \
      asm("v_cvt_pk_bf16_f32 %0, %1, %2" : "=v"(pd[j]) : "v"(e[2*j]), "v"(e[2*j+1])); \
    i32x4 lo = (i32x4){(int)pd[0],(int)pd[1],(int)pd[2],(int)pd[3]};            \
    i32x4 hi = (i32x4){(int)pd[4],(int)pd[5],(int)pd[6],(int)pd[7]};            \
    unsigned short* d = pb + (size_t)((mb32base + (MF))*2)*N_*16;               \
    *(i32x4*)d = lo;                                                            \
    *(i32x4*)(d + (size_t)N_*16) = hi;                                          \
  }

  #pragma unroll
  for (int it = 0; it < 4; it++){
    SEXP_BODY(2*it,     ka, kc, 2*it + 1)
    SEXP_BODY(2*it + 1, kc, ka, 2*it + 2)
  }
  SEXP_BODY(8, ka, kc, 8)
  #undef SEXP_BODY

  lsum += __shfl_xor(lsum, 32);
  if (l < 32)
    lsum_part[((size_t)bl*8 + ms*2 + mh)*N_ + n] = lsum;
}

// ---------------- PV GEMM v7: ZERO-LDS, barrier-free, direct-frag A+B ----------------
// out[b][c][n] = gamma * (sum_m V[c][m] P[n][m]) / lsum[n] + x[b][c][n]
// Tile 128c x 64n, 4 waves (wc=w&1: c-half 64, wn=w>>1: n-half 32). 36 K-steps.
// A (V): blocked vb chunks -> regs, 2-buf, 1 step ahead (8 x 16B/thr/step, 1KB/wave contig).
// B (P): Pl slabs -> regs, 3-buf, 2 steps ahead (4 x 16B/thr/step).
// No LDS, no barriers: per-wave counted s_waitcnt vmcnt(12) only.
__global__ __launch_bounds__(256) void k_pv(const unsigned short* __restrict__ vb,
                                            const unsigned short* __restrict__ Pl,
                                            const float* __restrict__ lsum_part,
                                            const float* __restrict__ x,
                                            const float* __restrict__ gamma_p,
                                            float* __restrict__ out,
                                            int b0, int bsh){
  int bid = blockIdx.x;
  int bl = bid & ((1 << bsh) - 1);
  int b = b0 + bl;
  int r = bid >> bsh;
  int cb = r & 3; int nb = r >> 2;          // cb 0..3, nb 0..35
  int c0 = cb*128, n0g = nb*64;
  int t = threadIdx.x; int w = t >> 6; int l = t & 63;
  int h = l >> 5, ln = l & 31;
  int wc = w & 1, wn = w >> 1;

  // --- A: per-lane bases into blocked vb (one per cf) ---
  const unsigned short* abase[2];
  #pragma unroll
  for (int cf = 0; cf < 2; cf++){
    int cg = cb*4 + wc*2 + cf;
    abase[cf] = vb + ((size_t)b*144*16 + cg)*512 + (ln*2 + h)*8;
  }
  // chunk step: m-block mbg -> + mbg*16*512 shorts = mbg*8192
  // --- B: per-lane offset into Pl slab ---
  const unsigned short* Pb = Pl + (size_t)bl*144*N_*16;
  size_t bstep = (size_t)N_*16;
  int boff = (n0g + wn*32 + ln)*16 + h*8;

  f32x16 acc[2];
  #pragma unroll
  for (int cf = 0; cf < 2; cf++)
    #pragma unroll
    for (int rr = 0; rr < 16; rr++) acc[cf][rr] = 0.f;

  bf16x8 A0[2][4], A1[2][4];        // A bufs (t even/odd)
  bf16x8 B0[4], B1[4], B2[4];       // B bufs (t mod 3)

  // ---- prologue: issue A(0), B(0), B(1); drain A(0)+B(0) ----
  #pragma unroll
  for (int cf = 0; cf < 2; cf++)
    #pragma unroll
    for (int mb = 0; mb < 4; mb++)
      A0[cf][mb] = *(const bf16x8*)(abase[cf] + (size_t)mb*8192);
  #pragma unroll
  for (int mb = 0; mb < 4; mb++)
    B0[mb] = *(const bf16x8*)(Pb + (size_t)mb*bstep + boff);
  #pragma unroll
  for (int mb = 0; mb < 4; mb++)
    B1[mb] = *(const bf16x8*)(Pb + (size_t)(4 + mb)*bstep + boff);
  asm volatile("s_waitcnt vmcnt(4)" ::: "memory");   // A(0),B(0) landed; B(1) in flight
  __builtin_amdgcn_sched_barrier(0);

  // STEP t: issue A(t+1) 8 + B(t+2) 4; vmcnt(12) drains A(t)+B(t+1)... (A(t) ready);
  // MFMA with A(t), B(t). In-order ledger keeps A(t+1)+B(t+2)=12 in flight.
  #define PV_STEP(KT, AC, AN, BC, BN)                                           \
  {                                                                             \
    int m1 = ((KT) + 1 < 36) ? ((KT) + 1)*4 : 0;                                \
    _Pragma("unroll")                                                           \
    for (int cf = 0; cf < 2; cf++)                                              \
      _Pragma("unroll")                                                         \
      for (int mb = 0; mb < 4; mb++)                                            \
        AN[cf][mb] = *(const bf16x8*)(abase[cf] + (size_t)(m1 + mb)*8192);      \
    {                                                                           \
      size_t mb2 = (size_t)((((KT) + 2 < 36) ? ((KT) + 2)*4 : 0));              \
      _Pragma("unroll")                                                         \
      for (int mb = 0; mb < 4; mb++)                                            \
        BN[mb] = *(const bf16x8*)(Pb + (mb2 + mb)*bstep + boff);                \
    }                                                                           \
    asm volatile("s_waitcnt vmcnt(12)" ::: "memory");                           \
    __builtin_amdgcn_sched_barrier(0);                                          \
    __builtin_amdgcn_s_setprio(1);                                              \
    _Pragma("unroll")                                                           \
    for (int cf = 0; cf < 2; cf++)                                              \
      _Pragma("unroll")                                                         \
      for (int mb = 0; mb < 4; mb++)                                            \
        acc[cf] = __builtin_amdgcn_mfma_f32_32x32x16_bf16(                      \
            AC[cf][mb], BC[mb], acc[cf], 0, 0, 0);                              \
    __builtin_amdgcn_s_setprio(0);                                              \
  }

  for (int it = 0; it < 6; it++){
    int kt = it*6;
    PV_STEP(kt+0, A0, A1, B0, B2)
    PV_STEP(kt+1, A1, A0, B1, B0)
    PV_STEP(kt+2, A0, A1, B2, B1)
    PV_STEP(kt+3, A1, A0, B0, B2)
    PV_STEP(kt+4, A0, A1, B1, B0)
    PV_STEP(kt+5, A1, A0, B2, B1)
  }
  #undef PV_STEP

  // ---- epilogue: out = gamma*(O/lsum) + x ----
  float gmv = gamma_p[0];
  {
    int n = n0g + wn*32 + ln;
    float s = 0.f;
    #pragma unroll
    for (int j = 0; j < 8; j++) s += lsum_part[((size_t)bl*8 + j)*N_ + n];
    float f = gmv / s;
    #pragma unroll
    for (int cf = 0; cf < 2; cf++){
      #pragma unroll
      for (int rr = 0; rr < 16; rr++){
        int c = c0 + wc*64 + cf*32 + (rr & 3) + 8*(rr >> 2) + 4*h;
        size_t idx = ((size_t)b*C_ + c)*N_ + n;
        out[idx] = acc[cf][rr]*f + x[idx];
      }
    }
  }
}

extern "C" void kernel_launch(void* const* d_in, const int* in_sizes, int n_in,
                              void* d_out, int out_size, void* d_ws, size_t ws_size,
                              hipStream_t stream) {
  (void)in_sizes; (void)n_in; (void)out_size;
  const float* x  = (const float*)d_in[0];
  const float* Wq = (const float*)d_in[1];
  const float* bq = (const float*)d_in[2];
  const float* Wk = (const float*)d_in[3];
  const float* bk = (const float*)d_in[4];
  const float* Wv = (const float*)d_in[5];
  const float* bv = (const float*)d_in[6];
  const float* gm = (const float*)d_in[7];
  float* out = (float*)d_out;

  const size_t qw_b = (size_t)B_*N_*CQ*2;
  const size_t vb_b = (size_t)B_*144*16*512*2;     // 18.87 MB (blocked V)
  const size_t wb_b = (size_t)640*512*2;

  int nbg = 8, bsh = 3;
  for (;;){
    size_t pl_b   = (size_t)nbg*144*N_*16*2;
    size_t lsum_b = (size_t)nbg*8*N_*4;
    size_t need   = pl_b + 2*qw_b + vb_b + lsum_b + wb_b;
    if (need <= ws_size || nbg == 1) break;
    nbg >>= 1; bsh--;
  }
  size_t pl_b   = (size_t)nbg*144*N_*16*2;
  size_t lsum_b = (size_t)nbg*8*N_*4;

  char* wsc = (char*)d_ws;
  unsigned short* Pl = (unsigned short*)wsc;
  unsigned short* qw = (unsigned short*)(wsc + pl_b);
  unsigned short* kw = (unsigned short*)(wsc + pl_b + qw_b);
  unsigned short* vb = (unsigned short*)(wsc + pl_b + 2*qw_b);
  float* lsum_part   = (float*)(wsc + pl_b + 2*qw_b + vb_b);
  unsigned short* Wb = (unsigned short*)(wsc + pl_b + 2*qw_b + vb_b + lsum_b);

  k_wcvt<<<160, 256, 0, stream>>>(Wq, Wk, Wv, Wb);
  k_prep<<<576, 512, 0, stream>>>(x, bq, bk, bv, Wb, qw, kw, vb);

  for (int b0 = 0; b0 < B_; b0 += nbg){
    k_sexp<<<144*nbg, 256, 0, stream>>>(qw, kw, Pl, lsum_part, b0, bsh);
    k_pv<<<144*nbg, 256, 0, stream>>>(vb, Pl, lsum_part, x, gm, out, b0, bsh);
  }
}

// Round 16
// 121.377 us; speedup vs baseline: 1.2479x; 1.2479x over previous
//
#include <hip/hip_runtime.h>

#define B_ 8
#define C_ 512
#define N_ 2304
#define CQ 64

typedef float f32x2 __attribute__((ext_vector_type(2)));
typedef float f32x4 __attribute__((ext_vector_type(4)));
typedef float f32x16 __attribute__((ext_vector_type(16)));
typedef short bf16x8 __attribute__((ext_vector_type(8)));
typedef unsigned short u16x4 __attribute__((ext_vector_type(4)));
typedef unsigned short u16x8 __attribute__((ext_vector_type(8)));
typedef int i32x4 __attribute__((ext_vector_type(4)));

__device__ __forceinline__ unsigned short f2bf(float f){
  union { float f; unsigned int u; } v; v.f = f;
  unsigned int r = (v.u + 0x7fffu + ((v.u >> 16) & 1u)) >> 16;
  return (unsigned short)r;
}

__device__ __forceinline__ void gload_lds16(const void* g, void* l){
  __builtin_amdgcn_global_load_lds(
      (const __attribute__((address_space(1))) unsigned int*)g,
      (__attribute__((address_space(3))) unsigned int*)l, 16, 0, 0);
}

// decode 8 fp8 (two u32) -> bf16x8 (slots in order)
__device__ __forceinline__ void fp8q_to_bf16(int w0, int w1, bf16x8* o){
  f32x2 a = __builtin_amdgcn_cvt_pk_f32_fp8(w0, false);
  f32x2 b = __builtin_amdgcn_cvt_pk_f32_fp8(w0, true);
  f32x2 c = __builtin_amdgcn_cvt_pk_f32_fp8(w1, false);
  f32x2 d = __builtin_amdgcn_cvt_pk_f32_fp8(w1, true);
  unsigned int u0,u1,u2,u3;
  asm("v_cvt_pk_bf16_f32 %0, %1, %2" : "=v"(u0) : "v"(a[0]), "v"(a[1]));
  asm("v_cvt_pk_bf16_f32 %0, %1, %2" : "=v"(u1) : "v"(b[0]), "v"(b[1]));
  asm("v_cvt_pk_bf16_f32 %0, %1, %2" : "=v"(u2) : "v"(c[0]), "v"(c[1]));
  asm("v_cvt_pk_bf16_f32 %0, %1, %2" : "=v"(u3) : "v"(d[0]), "v"(d[1]));
  union { unsigned int u[4]; bf16x8 v; } r;
  r.u[0]=u0; r.u[1]=u1; r.u[2]=u2; r.u[3]=u3;
  *o = r.v;
}

// ---------------- W -> bf16, MFMA-A-frag BLOCKED layout ----------------
__global__ __launch_bounds__(256) void k_wcvt(const float* __restrict__ Wq,
                                              const float* __restrict__ Wk,
                                              const float* __restrict__ Wv,
                                              unsigned short* __restrict__ Wb){
  int idx = blockIdx.x*256 + threadIdx.x;         // 40960 chunks
  int h = idx & 1, ln = (idx >> 1) & 31, cs = (idx >> 6) & 31, ob = idx >> 11;
  int row = ob*32 + ln, col = cs*16 + h*8;
  const float* src;
  if (row < 64)       src = Wq + (size_t)row*512 + col;
  else if (row < 128) src = Wk + (size_t)(row-64)*512 + col;
  else                src = Wv + (size_t)(row-128)*512 + col;
  f32x4 v0 = *(const f32x4*)src;
  f32x4 v1 = *(const f32x4*)(src + 4);
  u16x8 o;
  #pragma unroll
  for (int j = 0; j < 4; j++){ o[j] = f2bf(v0[j]); o[4+j] = f2bf(v1[j]); }
  *(u16x8*)(Wb + (size_t)idx*8) = o;
}

// ---------------- fused prep: transpose + Q/K/V projections (R14) ----------------
__global__ __launch_bounds__(512) void k_prep(const float* __restrict__ x,
                                              const float* __restrict__ bq,
                                              const float* __restrict__ bk,
                                              const float* __restrict__ bv,
                                              const unsigned short* __restrict__ Wb,
                                              unsigned short* __restrict__ qw,
                                              unsigned short* __restrict__ kw,
                                              unsigned short* __restrict__ vw){
  __shared__ short xt_l[32*520];          // 33.3 KB
  __shared__ float scr[2*32*68];          // 17.4 KB

  int i = blockIdx.x; int b = i & 7; int nt = i >> 3;
  int n0 = nt*32;
  int t = threadIdx.x; int w = t >> 6; int l = t & 63;
  int h = l >> 5, ln = l & 31;
  const size_t bN = (size_t)b*N_;

  // ---- phase 1: stage x -> xt_l ----
  #pragma unroll
  for (int it = 0; it < 8; it++){
    int c = it*64 + (t >> 3);
    int n4 = (t & 7)*4;
    f32x4 v = *(const f32x4*)(x + ((size_t)b*C_ + c)*N_ + n0 + n4);
    #pragma unroll
    for (int j = 0; j < 4; j++) xt_l[(n4+j)*520 + c] = (short)f2bf(v[j]);
  }
  __syncthreads();

  // ---- phase 2: GEMMs ----
  const unsigned short* wlane = Wb + (size_t)(ln*2 + h)*8;
  const unsigned short* wv0 = wlane + (size_t)(4 + 2*w)*16384;
  const unsigned short* wv1 = wlane + (size_t)(5 + 2*w)*16384;
  const unsigned short* wqk = wlane + (size_t)w*16384;

  f32x16 vacc[2]; f32x16 qkacc;
  #pragma unroll
  for (int rr = 0; rr < 16; rr++){ vacc[0][rr]=0.f; vacc[1][rr]=0.f; qkacc[rr]=0.f; }

  #pragma unroll 8
  for (int cs = 0; cs < 32; cs++){
    bf16x8 bx = *(const bf16x8*)&xt_l[ln*520 + cs*16 + h*8];
    bf16x8 a0 = *(const bf16x8*)(wv0 + (size_t)cs*512);
    bf16x8 a1 = *(const bf16x8*)(wv1 + (size_t)cs*512);
    vacc[0] = __builtin_amdgcn_mfma_f32_32x32x16_bf16(a0, bx, vacc[0], 0, 0, 0);
    vacc[1] = __builtin_amdgcn_mfma_f32_32x32x16_bf16(a1, bx, vacc[1], 0, 0, 0);
    if (w < 4){
      bf16x8 aq = *(const bf16x8*)(wqk + (size_t)cs*512);
      qkacc = __builtin_amdgcn_mfma_f32_32x32x16_bf16(aq, bx, qkacc, 0, 0, 0);
    }
  }

  // ---- phase 3a: Q/K scratch + cooperative store ----
  if (w < 4){
    float* s = scr + ((w >> 1) ? 2176 : 0);
    int obase = (w & 1)*32;
    #pragma unroll
    for (int rr = 0; rr < 16; rr++){
      int o = obase + (rr & 3) + 8*(rr >> 2) + 4*h;
      s[ln*68 + o] = qkacc[rr];
    }
  }
  __syncthreads();

  if (t < 256){
    int isK = t >> 7;
    int tt = t & 127;
    int n = tt >> 2, j = tt & 3;
    const float* s = scr + (isK ? 2176 : 0);
    const float* bias = isK ? bk : bq;
    float vals[16]; float sm = 0.f;
    #pragma unroll
    for (int ii = 0; ii < 16; ii++){
      vals[ii] = s[n*68 + j*16 + ii] + bias[j*16 + ii];
      sm += vals[ii];
    }
    sm += __shfl_xor(sm, 1); sm += __shfl_xor(sm, 2);
    float mean = isK ? 0.f : sm * (1.f/64.f);
    float scl  = isK ? 1.f : (1.44269504089f/512.f);
    u16x8 h0, h1;
    #pragma unroll
    for (int ii = 0; ii < 8; ii++) h0[ii] = f2bf((vals[ii]   - mean)*scl);
    #pragma unroll
    for (int ii = 0; ii < 8; ii++) h1[ii] = f2bf((vals[8+ii] - mean)*scl);
    unsigned short* d = (isK ? kw : qw) + (bN + n0 + n)*CQ + j*16;
    *(u16x8*)d = h0;
    *(u16x8*)(d + 8) = h1;
  }
  __syncthreads();

  // ---- phase 3b: V epilogue, 4 rounds x 2 chunks of 64 o ----
  #pragma unroll
  for (int r = 0; r < 4; r++){
    if ((w >> 1) == r){
      float* s = scr + (w & 1)*2176;
      #pragma unroll
      for (int of = 0; of < 2; of++)
        #pragma unroll
        for (int rr = 0; rr < 16; rr++){
          int o = of*32 + (rr & 3) + 8*(rr >> 2) + 4*h;
          s[ln*68 + o] = vacc[of][rr];
        }
    }
    __syncthreads();
    {
      int ch = t >> 8;
      int tt = t & 255;
      int o = tt >> 2, jj = (tt >> 1) & 1, half = tt & 1;
      int og = (2*r + ch)*64 + o;
      const float* s = scr + ch*2176;
      float bvv = bv[og];
      u16x8 hv;
      #pragma unroll
      for (int ii = 0; ii < 8; ii++){
        int q2 = ((ii & 3) | ((ii & 4) << 1)) + half*4;
        hv[ii] = f2bf(s[(jj*16 + q2)*68 + o] + bvv);
      }
      *(u16x8*)(vw + ((size_t)b*C_ + og)*N_ + n0 + jj*16 + half*8) = hv;
    }
    __syncthreads();
  }
}

// ---------------- S + exp2 -> P fp8 (pair-blocked frag-ready layout) ----------------
// Plf pair chunk: byte off = ((bl*72 + pair)*N + n)*32 + h*16 + sub*8
// sub 0/1 = m-block 2*pair / 2*pair+1, 8 fp8 slots (h*8..h*8+7).
__global__ __launch_bounds__(256) void k_sexp(const unsigned short* __restrict__ qw,
                                              const unsigned short* __restrict__ kw,
                                              unsigned char* __restrict__ Plf,
                                              float* __restrict__ lsum_part,
                                              int b0, int bsh){
  int bid = blockIdx.x;
  int bl = bid & ((1 << bsh) - 1);
  int b = b0 + bl;
  int r = bid >> bsh;
  int ms = r & 3; int nt = r >> 2;
  int t = threadIdx.x; int w = t >> 6; int l = t & 63;
  int h = l >> 5, ln = l & 31;
  int nf = w & 1, mh = w >> 1;
  int n = nt*64 + nf*32 + ln;

  const unsigned short* qb = qw + ((size_t)b*N_ + n)*CQ + h*8;
  bf16x8 qf[4];
  #pragma unroll
  for (int kq = 0; kq < 4; kq++) qf[kq] = *(const bf16x8*)(qb + kq*16);

  int mb32base = ms*18 + mh*9;
  const unsigned short* ks0 = kw + ((size_t)b*N_ + ln)*CQ + h*8 + (size_t)mb32base*32*CQ;
  unsigned char* pbf = Plf + (((size_t)bl*72*N_ + n)*32) + h*16;

  float lsum = 0.f;
  bf16x8 ka[4], kc[4];
  #pragma unroll
  for (int kq = 0; kq < 4; kq++) ka[kq] = *(const bf16x8*)(ks0 + kq*16);

  #define SEXP_BODY(MF, KF, KN, PFOFF)                                          \
  {                                                                             \
    _Pragma("unroll")                                                           \
    for (int kq = 0; kq < 4; kq++)                                              \
      KN[kq] = *(const bf16x8*)(ks0 + (size_t)(PFOFF)*32*CQ + kq*16);           \
    f32x16 sv;                                                                  \
    _Pragma("unroll")                                                           \
    for (int rr = 0; rr < 16; rr++) sv[rr] = 0.f;                               \
    _Pragma("unroll")                                                           \
    for (int kq = 0; kq < 4; kq++)                                              \
      sv = __builtin_amdgcn_mfma_f32_32x32x16_bf16(KF[kq], qf[kq], sv, 0, 0, 0);\
    float e[16];                                                                \
    _Pragma("unroll")                                                           \
    for (int rr = 0; rr < 16; rr++) e[rr] = exp2f(sv[rr]);                      \
    _Pragma("unroll")                                                           \
    for (int rr = 0; rr < 16; rr++) lsum += e[rr];                              \
    int w0 = __builtin_amdgcn_cvt_pk_fp8_f32(e[0],  e[1],  0,  false);          \
    w0     = __builtin_amdgcn_cvt_pk_fp8_f32(e[2],  e[3],  w0, true);           \
    int w1 = __builtin_amdgcn_cvt_pk_fp8_f32(e[4],  e[5],  0,  false);          \
    w1     = __builtin_amdgcn_cvt_pk_fp8_f32(e[6],  e[7],  w1, true);           \
    int w2 = __builtin_amdgcn_cvt_pk_fp8_f32(e[8],  e[9],  0,  false);          \
    w2     = __builtin_amdgcn_cvt_pk_fp8_f32(e[10], e[11], w2, true);           \
    int w3 = __builtin_amdgcn_cvt_pk_fp8_f32(e[12], e[13], 0,  false);          \
    w3     = __builtin_amdgcn_cvt_pk_fp8_f32(e[14], e[15], w3, true);           \
    i32x4 pk4 = (i32x4){w0, w1, w2, w3};                                        \
    *(i32x4*)(pbf + (size_t)(mb32base + (MF))*((size_t)N_*32)) = pk4;           \
  }

  #pragma unroll
  for (int it = 0; it < 4; it++){
    SEXP_BODY(2*it,     ka, kc, 2*it + 1)
    SEXP_BODY(2*it + 1, kc, ka, 2*it + 2)
  }
  SEXP_BODY(8, ka, kc, 8)
  #undef SEXP_BODY

  lsum += __shfl_xor(lsum, 32);
  if (l < 32)
    lsum_part[((size_t)bl*8 + ms*2 + mh)*N_ + n] = lsum;
}

// ---------------- PV GEMM (R14 pipeline, fp8 B): 128c x 64n, BK=64 ----------------
// A (V): LDS 3-buf [128c][64m] rotate-swizzled, staged 2 ahead (4 gload_lds/thr/step).
// B (P): fp8 pair-chunks global->reg 3-buf 2-deep (2 x 16B/thr/step), decoded to
// bf16 in VALU right before the (verified) bf16 MFMA. One s_barrier/step,
// counted s_waitcnt vmcnt(8) lgkmcnt(0): in-flight B(t+1)2 + A(t+2)4 + B(t+2)2 = 8.
__global__ __launch_bounds__(256, 1) void k_pv(const unsigned short* __restrict__ vw,
                                               const unsigned char* __restrict__ Plf,
                                               const float* __restrict__ lsum_part,
                                               const float* __restrict__ x,
                                               const float* __restrict__ gamma_p,
                                               float* __restrict__ out,
                                               int b0, int bsh){
  __shared__ __attribute__((aligned(16))) short At[3][128*64];   // 3 x 16 KB

  int bid = blockIdx.x;
  int bl = bid & ((1 << bsh) - 1);
  int b = b0 + bl;
  int r = bid >> bsh;
  int cb = r & 3; int nb = r >> 2;          // cb 0..3, nb 0..35
  int c0 = cb*128, n0g = nb*64;
  int t = threadIdx.x; int w = t >> 6; int l = t & 63;
  int h = l >> 5, ln = l & 31;
  int wc = w & 1, wn = w >> 1;

  // --- A staging (R14) ---
  int gc = ((l & 7) - (l >> 3)) & 7;
  const unsigned short* asrc0 = vw + ((size_t)b*C_ + c0 + w*32 + (l >> 3))*N_ + gc*8;
  int aro[2][4];
  #pragma unroll
  for (int cf = 0; cf < 2; cf++)
    #pragma unroll
    for (int mb = 0; mb < 4; mb++){
      int row = wc*64 + cf*32 + ln;
      aro[cf][mb] = (row*8 + ((mb*2 + h + row) & 7)) * 16;
    }
  // --- B: fp8 pair-chunk per-lane offset ---
  const unsigned char* Pbf = Plf + (size_t)bl*72*N_*32;
  size_t pstep = (size_t)N_*32;              // one pair (bytes)
  size_t boffB = (size_t)(n0g + wn*32 + ln)*32 + h*16;

  f32x16 acc[2];
  #pragma unroll
  for (int cf = 0; cf < 2; cf++)
    #pragma unroll
    for (int rr = 0; rr < 16; rr++) acc[cf][rr] = 0.f;

  i32x4 B0[2], B1[2], B2[2];   // raw fp8 pair-chunks (2 pairs per step)

  // ---- prologue: stage A(0), load B(0); stage A(1), load B(1) ----
  #pragma unroll
  for (int j = 0; j < 4; j++)
    gload_lds16(asrc0 + (size_t)j*8*N_, &At[0][w*2048 + j*512]);
  B0[0] = *(const i32x4*)(Pbf + boffB);
  B0[1] = *(const i32x4*)(Pbf + pstep + boffB);
  #pragma unroll
  for (int j = 0; j < 4; j++)
    gload_lds16(asrc0 + (size_t)j*8*N_ + 64, &At[1][w*2048 + j*512]);
  B1[0] = *(const i32x4*)(Pbf + 2*pstep + boffB);
  B1[1] = *(const i32x4*)(Pbf + 3*pstep + boffB);
  asm volatile("s_waitcnt vmcnt(8)" ::: "memory");   // A(0) landed
  __builtin_amdgcn_s_barrier();
  __builtin_amdgcn_sched_barrier(0);

  #define PV_STEP(KT, RD, WR, BC, BN)                                           \
  {                                                                             \
    const char* Ab = (const char*)At[RD];                                       \
    bf16x8 a_[2][4];                                                            \
    _Pragma("unroll")                                                           \
    for (int cf = 0; cf < 2; cf++)                                              \
      _Pragma("unroll")                                                         \
      for (int mb = 0; mb < 4; mb++)                                            \
        a_[cf][mb] = *(const bf16x8*)(Ab + aro[cf][mb]);                        \
    int m2 = ((KT) + 2 < 36) ? ((KT) + 2)*64 : 0;                               \
    _Pragma("unroll")                                                           \
    for (int j = 0; j < 4; j++)                                                 \
      gload_lds16(asrc0 + (size_t)j*8*N_ + m2, &At[WR][w*2048 + j*512]);        \
    {                                                                           \
      size_t pr2 = (size_t)((((KT) + 2 < 36) ? ((KT) + 2)*2 : 0));              \
      BN[0] = *(const i32x4*)(Pbf + pr2*pstep + boffB);                         \
      BN[1] = *(const i32x4*)(Pbf + (pr2 + 1)*pstep + boffB);                   \
    }                                                                           \
    bf16x8 bfr[4];                                                              \
    fp8q_to_bf16(BC[0][0], BC[0][1], &bfr[0]);                                  \
    fp8q_to_bf16(BC[0][2], BC[0][3], &bfr[1]);                                  \
    fp8q_to_bf16(BC[1][0], BC[1][1], &bfr[2]);                                  \
    fp8q_to_bf16(BC[1][2], BC[1][3], &bfr[3]);                                  \
    _Pragma("unroll")                                                           \
    for (int cf = 0; cf < 2; cf++)                                              \
      _Pragma("unroll")                                                         \
      for (int mb = 0; mb < 4; mb++)                                            \
        acc[cf] = __builtin_amdgcn_mfma_f32_32x32x16_bf16(                      \
            a_[cf][mb], bfr[mb], acc[cf], 0, 0, 0);                             \
    asm volatile("s_waitcnt vmcnt(8) lgkmcnt(0)" ::: "memory");                 \
    __builtin_amdgcn_s_barrier();                                               \
    __builtin_amdgcn_sched_barrier(0);                                          \
  }

  for (int it = 0; it < 6; it++){
    int kt = it*6;
    PV_STEP(kt+0, 0, 2, B0, B2)
    PV_STEP(kt+1, 1, 0, B1, B0)
    PV_STEP(kt+2, 2, 1, B2, B1)
    PV_STEP(kt+3, 0, 2, B0, B2)
    PV_STEP(kt+4, 1, 0, B1, B0)
    PV_STEP(kt+5, 2, 1, B2, B1)
  }
  #undef PV_STEP

  // ---- epilogue: out = gamma*(O/lsum) + x ----
  float gmv = gamma_p[0];
  {
    int n = n0g + wn*32 + ln;
    float s = 0.f;
    #pragma unroll
    for (int j = 0; j < 8; j++) s += lsum_part[((size_t)bl*8 + j)*N_ + n];
    float f = gmv / s;
    #pragma unroll
    for (int cf = 0; cf < 2; cf++){
      #pragma unroll
      for (int rr = 0; rr < 16; rr++){
        int c = c0 + wc*64 + cf*32 + (rr & 3) + 8*(rr >> 2) + 4*h;
        size_t idx = ((size_t)b*C_ + c)*N_ + n;
        out[idx] = acc[cf][rr]*f + x[idx];
      }
    }
  }
}

extern "C" void kernel_launch(void* const* d_in, const int* in_sizes, int n_in,
                              void* d_out, int out_size, void* d_ws, size_t ws_size,
                              hipStream_t stream) {
  (void)in_sizes; (void)n_in; (void)out_size;
  const float* x  = (const float*)d_in[0];
  const float* Wq = (const float*)d_in[1];
  const float* bq = (const float*)d_in[2];
  const float* Wk = (const float*)d_in[3];
  const float* bk = (const float*)d_in[4];
  const float* Wv = (const float*)d_in[5];
  const float* bv = (const float*)d_in[6];
  const float* gm = (const float*)d_in[7];
  float* out = (float*)d_out;

  const size_t qw_b = (size_t)B_*N_*CQ*2;
  const size_t vw_b = (size_t)B_*C_*N_*2;
  const size_t wb_b = (size_t)640*512*2;

  int nbg = 8, bsh = 3;
  for (;;){
    size_t pl_b   = (size_t)nbg*72*N_*32;      // fp8 P, pair-blocked
    size_t lsum_b = (size_t)nbg*8*N_*4;
    size_t need   = pl_b + 2*qw_b + vw_b + lsum_b + wb_b;
    if (need <= ws_size || nbg == 1) break;
    nbg >>= 1; bsh--;
  }
  size_t pl_b   = (size_t)nbg*72*N_*32;
  size_t lsum_b = (size_t)nbg*8*N_*4;

  char* wsc = (char*)d_ws;
  unsigned char* Plf = (unsigned char*)wsc;
  unsigned short* qw = (unsigned short*)(wsc + pl_b);
  unsigned short* kw = (unsigned short*)(wsc + pl_b + qw_b);
  unsigned short* vw = (unsigned short*)(wsc + pl_b + 2*qw_b);
  float* lsum_part   = (float*)(wsc + pl_b + 2*qw_b + vw_b);
  unsigned short* Wb = (unsigned short*)(wsc + pl_b + 2*qw_b + vw_b + lsum_b);

  k_wcvt<<<160, 256, 0, stream>>>(Wq, Wk, Wv, Wb);
  k_prep<<<576, 512, 0, stream>>>(x, bq, bk, bv, Wb, qw, kw, vw);

  for (int b0 = 0; b0 < B_; b0 += nbg){
    k_sexp<<<144*nbg, 256, 0, stream>>>(qw, kw, Plf, lsum_part, b0, bsh);
    k_pv<<<144*nbg, 256, 0, stream>>>(vw, Plf, lsum_part, x, gm, out, b0, bsh);
  }
}

// Round 17
// 110.545 us; speedup vs baseline: 1.3701x; 1.0980x over previous
//
#include <hip/hip_runtime.h>

#define B_ 8
#define C_ 512
#define N_ 2304
#define CQ 64

typedef float f32x2 __attribute__((ext_vector_type(2)));
typedef float f32x4 __attribute__((ext_vector_type(4)));
typedef float f32x16 __attribute__((ext_vector_type(16)));
typedef short bf16x8 __attribute__((ext_vector_type(8)));
typedef unsigned short u16x4 __attribute__((ext_vector_type(4)));
typedef unsigned short u16x8 __attribute__((ext_vector_type(8)));
typedef int i32x2 __attribute__((ext_vector_type(2)));
typedef int i32x4 __attribute__((ext_vector_type(4)));

__device__ __forceinline__ unsigned short f2bf(float f){
  union { float f; unsigned int u; } v; v.f = f;
  unsigned int r = (v.u + 0x7fffu + ((v.u >> 16) & 1u)) >> 16;
  return (unsigned short)r;
}

__device__ __forceinline__ void gload_lds16(const void* g, void* l){
  __builtin_amdgcn_global_load_lds(
      (const __attribute__((address_space(1))) unsigned int*)g,
      (__attribute__((address_space(3))) unsigned int*)l, 16, 0, 0);
}

// ---------------- W -> bf16, MFMA-A-frag BLOCKED layout ----------------
__global__ __launch_bounds__(256) void k_wcvt(const float* __restrict__ Wq,
                                              const float* __restrict__ Wk,
                                              const float* __restrict__ Wv,
                                              unsigned short* __restrict__ Wb){
  int idx = blockIdx.x*256 + threadIdx.x;         // 40960 chunks
  int h = idx & 1, ln = (idx >> 1) & 31, cs = (idx >> 6) & 31, ob = idx >> 11;
  int row = ob*32 + ln, col = cs*16 + h*8;
  const float* src;
  if (row < 64)       src = Wq + (size_t)row*512 + col;
  else if (row < 128) src = Wk + (size_t)(row-64)*512 + col;
  else                src = Wv + (size_t)(row-128)*512 + col;
  f32x4 v0 = *(const f32x4*)src;
  f32x4 v1 = *(const f32x4*)(src + 4);
  u16x8 o;
  #pragma unroll
  for (int j = 0; j < 4; j++){ o[j] = f2bf(v0[j]); o[4+j] = f2bf(v1[j]); }
  *(u16x8*)(Wb + (size_t)idx*8) = o;
}

// ---------------- fused prep: transpose + Q/K/V projections ----------------
// V output: fp8 e4m3 [B][C][N] bytes, m-perm (bit2<->bit3 pairing) as before.
__global__ __launch_bounds__(512) void k_prep(const float* __restrict__ x,
                                              const float* __restrict__ bq,
                                              const float* __restrict__ bk,
                                              const float* __restrict__ bv,
                                              const unsigned short* __restrict__ Wb,
                                              unsigned short* __restrict__ qw,
                                              unsigned short* __restrict__ kw,
                                              unsigned char* __restrict__ vw8){
  __shared__ short xt_l[32*520];          // 33.3 KB
  __shared__ float scr[2*32*68];          // 17.4 KB

  int i = blockIdx.x; int b = i & 7; int nt = i >> 3;
  int n0 = nt*32;
  int t = threadIdx.x; int w = t >> 6; int l = t & 63;
  int h = l >> 5, ln = l & 31;
  const size_t bN = (size_t)b*N_;

  // ---- phase 1: stage x -> xt_l ----
  #pragma unroll
  for (int it = 0; it < 8; it++){
    int c = it*64 + (t >> 3);
    int n4 = (t & 7)*4;
    f32x4 v = *(const f32x4*)(x + ((size_t)b*C_ + c)*N_ + n0 + n4);
    #pragma unroll
    for (int j = 0; j < 4; j++) xt_l[(n4+j)*520 + c] = (short)f2bf(v[j]);
  }
  __syncthreads();

  // ---- phase 2: GEMMs ----
  const unsigned short* wlane = Wb + (size_t)(ln*2 + h)*8;
  const unsigned short* wv0 = wlane + (size_t)(4 + 2*w)*16384;
  const unsigned short* wv1 = wlane + (size_t)(5 + 2*w)*16384;
  const unsigned short* wqk = wlane + (size_t)w*16384;

  f32x16 vacc[2]; f32x16 qkacc;
  #pragma unroll
  for (int rr = 0; rr < 16; rr++){ vacc[0][rr]=0.f; vacc[1][rr]=0.f; qkacc[rr]=0.f; }

  #pragma unroll 8
  for (int cs = 0; cs < 32; cs++){
    bf16x8 bx = *(const bf16x8*)&xt_l[ln*520 + cs*16 + h*8];
    bf16x8 a0 = *(const bf16x8*)(wv0 + (size_t)cs*512);
    bf16x8 a1 = *(const bf16x8*)(wv1 + (size_t)cs*512);
    vacc[0] = __builtin_amdgcn_mfma_f32_32x32x16_bf16(a0, bx, vacc[0], 0, 0, 0);
    vacc[1] = __builtin_amdgcn_mfma_f32_32x32x16_bf16(a1, bx, vacc[1], 0, 0, 0);
    if (w < 4){
      bf16x8 aq = *(const bf16x8*)(wqk + (size_t)cs*512);
      qkacc = __builtin_amdgcn_mfma_f32_32x32x16_bf16(aq, bx, qkacc, 0, 0, 0);
    }
  }

  // ---- phase 3a: Q/K scratch + cooperative store ----
  if (w < 4){
    float* s = scr + ((w >> 1) ? 2176 : 0);
    int obase = (w & 1)*32;
    #pragma unroll
    for (int rr = 0; rr < 16; rr++){
      int o = obase + (rr & 3) + 8*(rr >> 2) + 4*h;
      s[ln*68 + o] = qkacc[rr];
    }
  }
  __syncthreads();

  if (t < 256){
    int isK = t >> 7;
    int tt = t & 127;
    int n = tt >> 2, j = tt & 3;
    const float* s = scr + (isK ? 2176 : 0);
    const float* bias = isK ? bk : bq;
    float vals[16]; float sm = 0.f;
    #pragma unroll
    for (int ii = 0; ii < 16; ii++){
      vals[ii] = s[n*68 + j*16 + ii] + bias[j*16 + ii];
      sm += vals[ii];
    }
    sm += __shfl_xor(sm, 1); sm += __shfl_xor(sm, 2);
    float mean = isK ? 0.f : sm * (1.f/64.f);
    float scl  = isK ? 1.f : (1.44269504089f/512.f);
    u16x8 h0, h1;
    #pragma unroll
    for (int ii = 0; ii < 8; ii++) h0[ii] = f2bf((vals[ii]   - mean)*scl);
    #pragma unroll
    for (int ii = 0; ii < 8; ii++) h1[ii] = f2bf((vals[8+ii] - mean)*scl);
    unsigned short* d = (isK ? kw : qw) + (bN + n0 + n)*CQ + j*16;
    *(u16x8*)d = h0;
    *(u16x8*)(d + 8) = h1;
  }
  __syncthreads();

  // ---- phase 3b: V epilogue -> fp8, 4 rounds x 2 chunks of 64 o ----
  #pragma unroll
  for (int r = 0; r < 4; r++){
    if ((w >> 1) == r){
      float* s = scr + (w & 1)*2176;
      #pragma unroll
      for (int of = 0; of < 2; of++)
        #pragma unroll
        for (int rr = 0; rr < 16; rr++){
          int o = of*32 + (rr & 3) + 8*(rr >> 2) + 4*h;
          s[ln*68 + o] = vacc[of][rr];
        }
    }
    __syncthreads();
    {
      int ch = t >> 8;
      int tt = t & 255;
      int o = tt >> 2, jj = (tt >> 1) & 1, half = tt & 1;
      int og = (2*r + ch)*64 + o;
      const float* s = scr + ch*2176;
      float bvv = bv[og];
      float vv[8];
      #pragma unroll
      for (int ii = 0; ii < 8; ii++){
        int q2 = ((ii & 3) | ((ii & 4) << 1)) + half*4;   // swap bits 2,3 of pos
        vv[ii] = s[(jj*16 + q2)*68 + o] + bvv;
      }
      int w0 = __builtin_amdgcn_cvt_pk_fp8_f32(vv[0], vv[1], 0,  false);
      w0     = __builtin_amdgcn_cvt_pk_fp8_f32(vv[2], vv[3], w0, true);
      int w1 = __builtin_amdgcn_cvt_pk_fp8_f32(vv[4], vv[5], 0,  false);
      w1     = __builtin_amdgcn_cvt_pk_fp8_f32(vv[6], vv[7], w1, true);
      size_t dst = ((size_t)b*C_ + og)*N_ + n0 + jj*16 + half*8;
      *(i32x2*)(vw8 + dst) = (i32x2){w0, w1};
    }
    __syncthreads();
  }
}

// ---------------- S + exp2 -> P fp8 (pair-blocked frag-ready layout) ----------------
__global__ __launch_bounds__(256) void k_sexp(const unsigned short* __restrict__ qw,
                                              const unsigned short* __restrict__ kw,
                                              unsigned char* __restrict__ Plf,
                                              float* __restrict__ lsum_part,
                                              int b0, int bsh){
  int bid = blockIdx.x;
  int bl = bid & ((1 << bsh) - 1);
  int b = b0 + bl;
  int r = bid >> bsh;
  int ms = r & 3; int nt = r >> 2;
  int t = threadIdx.x; int w = t >> 6; int l = t & 63;
  int h = l >> 5, ln = l & 31;
  int nf = w & 1, mh = w >> 1;
  int n = nt*64 + nf*32 + ln;

  const unsigned short* qb = qw + ((size_t)b*N_ + n)*CQ + h*8;
  bf16x8 qf[4];
  #pragma unroll
  for (int kq = 0; kq < 4; kq++) qf[kq] = *(const bf16x8*)(qb + kq*16);

  int mb32base = ms*18 + mh*9;
  const unsigned short* ks0 = kw + ((size_t)b*N_ + ln)*CQ + h*8 + (size_t)mb32base*32*CQ;
  unsigned char* pbf = Plf + (((size_t)bl*72*N_ + n)*32) + h*16;

  float lsum = 0.f;
  bf16x8 ka[4], kc[4];
  #pragma unroll
  for (int kq = 0; kq < 4; kq++) ka[kq] = *(const bf16x8*)(ks0 + kq*16);

  #define SEXP_BODY(MF, KF, KN, PFOFF)                                          \
  {                                                                             \
    _Pragma("unroll")                                                           \
    for (int kq = 0; kq < 4; kq++)                                              \
      KN[kq] = *(const bf16x8*)(ks0 + (size_t)(PFOFF)*32*CQ + kq*16);           \
    f32x16 sv;                                                                  \
    _Pragma("unroll")                                                           \
    for (int rr = 0; rr < 16; rr++) sv[rr] = 0.f;                               \
    _Pragma("unroll")                                                           \
    for (int kq = 0; kq < 4; kq++)                                              \
      sv = __builtin_amdgcn_mfma_f32_32x32x16_bf16(KF[kq], qf[kq], sv, 0, 0, 0);\
    float e[16];                                                                \
    _Pragma("unroll")                                                           \
    for (int rr = 0; rr < 16; rr++) e[rr] = exp2f(sv[rr]);                      \
    _Pragma("unroll")                                                           \
    for (int rr = 0; rr < 16; rr++) lsum += e[rr];                              \
    int w0 = __builtin_amdgcn_cvt_pk_fp8_f32(e[0],  e[1],  0,  false);          \
    w0     = __builtin_amdgcn_cvt_pk_fp8_f32(e[2],  e[3],  w0, true);           \
    int w1 = __builtin_amdgcn_cvt_pk_fp8_f32(e[4],  e[5],  0,  false);          \
    w1     = __builtin_amdgcn_cvt_pk_fp8_f32(e[6],  e[7],  w1, true);           \
    int w2 = __builtin_amdgcn_cvt_pk_fp8_f32(e[8],  e[9],  0,  false);          \
    w2     = __builtin_amdgcn_cvt_pk_fp8_f32(e[10], e[11], w2, true);           \
    int w3 = __builtin_amdgcn_cvt_pk_fp8_f32(e[12], e[13], 0,  false);          \
    w3     = __builtin_amdgcn_cvt_pk_fp8_f32(e[14], e[15], w3, true);           \
    i32x4 pk4 = (i32x4){w0, w1, w2, w3};                                        \
    *(i32x4*)(pbf + (size_t)(mb32base + (MF))*((size_t)N_*32)) = pk4;           \
  }

  #pragma unroll
  for (int it = 0; it < 4; it++){
    SEXP_BODY(2*it,     ka, kc, 2*it + 1)
    SEXP_BODY(2*it + 1, kc, ka, 2*it + 2)
  }
  SEXP_BODY(8, ka, kc, 8)
  #undef SEXP_BODY

  lsum += __shfl_xor(lsum, 32);
  if (l < 32)
    lsum_part[((size_t)bl*8 + ms*2 + mh)*N_ + n] = lsum;
}

// ---------------- PV GEMM: full-fp8 MFMA, 128c x 64n, BK=64, R14 pipeline ----------------
// A (V fp8): LDS 3-buf [128c][64m] 8KB, rotate pos=(g+row+(row>>2))&3, staged 2 ahead
//   (2 gload_lds/thr/step). Frag = ds_read_b64 (~2-way conflict = free).
// B (P fp8): pair-chunks global->reg 3-buf 2-deep (2 x 16B/thr/step); 8B halves feed
//   MFMA B directly (zero decode). mfma_f32_32x32x16_fp8_fp8 (= bf16 rate).
// One s_barrier/step + counted vmcnt(6) lgkmcnt(0): B(t+1)2 + A(t+2)2 + B(t+2)2.
__global__ __launch_bounds__(256, 1) void k_pv(const unsigned char* __restrict__ vw8,
                                               const unsigned char* __restrict__ Plf,
                                               const float* __restrict__ lsum_part,
                                               const float* __restrict__ x,
                                               const float* __restrict__ gamma_p,
                                               float* __restrict__ out,
                                               int b0, int bsh){
  __shared__ __attribute__((aligned(16))) char At[3][8192];   // 3 x 8 KB

  int bid = blockIdx.x;
  int bl = bid & ((1 << bsh) - 1);
  int b = b0 + bl;
  int r = bid >> bsh;
  int cb = r & 3; int nb = r >> 2;          // cb 0..3, nb 0..35
  int c0 = cb*128, n0g = nb*64;
  int t = threadIdx.x; int w = t >> 6; int l = t & 63;
  int h = l >> 5, ln = l & 31;
  int wc = w & 1, wn = w >> 1;

  // --- A staging: thread covers granules G = j*256 + t (j=0,1); row=G>>2, pos=G&3 ---
  const unsigned char* asrc[2];
  int adst[2];
  #pragma unroll
  for (int j = 0; j < 2; j++){
    int row = j*64 + (t >> 2);
    int pos = t & 3;
    int f = (row + (row >> 2)) & 3;
    int q = (pos - f) & 3;
    asrc[j] = vw8 + ((size_t)b*C_ + c0 + row)*N_ + q*16;    // + m0 bytes
    adst[j] = j*4096 + w*1024;                               // + lane*16 implicit
  }
  // --- A frag read byte offsets: row=wc*64+cf*32+ln, chunk mb, half h ---
  int aro[2][4];
  #pragma unroll
  for (int cf = 0; cf < 2; cf++)
    #pragma unroll
    for (int mb = 0; mb < 4; mb++){
      int row = wc*64 + cf*32 + ln;
      int f = (row + (row >> 2)) & 3;
      aro[cf][mb] = row*64 + ((mb + f) & 3)*16 + h*8;
    }
  // --- B: fp8 pair-chunk per-lane offset ---
  const unsigned char* Pbf = Plf + (size_t)bl*72*N_*32;
  size_t pstep = (size_t)N_*32;              // one pair (bytes)
  size_t boffB = (size_t)(n0g + wn*32 + ln)*32 + h*16;

  f32x16 acc[2];
  #pragma unroll
  for (int cf = 0; cf < 2; cf++)
    #pragma unroll
    for (int rr = 0; rr < 16; rr++) acc[cf][rr] = 0.f;

  union bu { i32x4 v; long lg[2]; };
  bu B0[2], B1[2], B2[2];   // raw fp8 pair-chunks (2 pairs per step)

  // ---- prologue: stage A(0), load B(0); stage A(1), load B(1) ----
  #pragma unroll
  for (int j = 0; j < 2; j++)
    gload_lds16(asrc[j], At[0] + adst[j]);
  B0[0].v = *(const i32x4*)(Pbf + boffB);
  B0[1].v = *(const i32x4*)(Pbf + pstep + boffB);
  #pragma unroll
  for (int j = 0; j < 2; j++)
    gload_lds16(asrc[j] + 64, At[1] + adst[j]);
  B1[0].v = *(const i32x4*)(Pbf + 2*pstep + boffB);
  B1[1].v = *(const i32x4*)(Pbf + 3*pstep + boffB);
  asm volatile("s_waitcnt vmcnt(6)" ::: "memory");   // A(0) landed
  __builtin_amdgcn_s_barrier();
  __builtin_amdgcn_sched_barrier(0);

  #define PV_STEP(KT, RD, WR, BC, BN)                                           \
  {                                                                             \
    const char* Ab = (const char*)At[RD];                                       \
    long a_[2][4];                                                              \
    _Pragma("unroll")                                                           \
    for (int cf = 0; cf < 2; cf++)                                              \
      _Pragma("unroll")                                                         \
      for (int mb = 0; mb < 4; mb++)                                            \
        a_[cf][mb] = *(const long*)(Ab + aro[cf][mb]);                          \
    int m2 = ((KT) + 2 < 36) ? ((KT) + 2)*64 : 0;                               \
    _Pragma("unroll")                                                           \
    for (int j = 0; j < 2; j++)                                                 \
      gload_lds16(asrc[j] + m2, At[WR] + adst[j]);                              \
    {                                                                           \
      size_t pr2 = (size_t)((((KT) + 2 < 36) ? ((KT) + 2)*2 : 0));              \
      BN[0].v = *(const i32x4*)(Pbf + pr2*pstep + boffB);                       \
      BN[1].v = *(const i32x4*)(Pbf + (pr2 + 1)*pstep + boffB);                 \
    }                                                                           \
    _Pragma("unroll")                                                           \
    for (int cf = 0; cf < 2; cf++)                                              \
      _Pragma("unroll")                                                         \
      for (int mb = 0; mb < 4; mb++)                                            \
        acc[cf] = __builtin_amdgcn_mfma_f32_32x32x16_fp8_fp8(                   \
            a_[cf][mb], BC[mb >> 1].lg[mb & 1], acc[cf], 0, 0, 0);              \
    asm volatile("s_waitcnt vmcnt(6) lgkmcnt(0)" ::: "memory");                 \
    __builtin_amdgcn_s_barrier();                                               \
    __builtin_amdgcn_sched_barrier(0);                                          \
  }

  for (int it = 0; it < 6; it++){
    int kt = it*6;
    PV_STEP(kt+0, 0, 2, B0, B2)
    PV_STEP(kt+1, 1, 0, B1, B0)
    PV_STEP(kt+2, 2, 1, B2, B1)
    PV_STEP(kt+3, 0, 2, B0, B2)
    PV_STEP(kt+4, 1, 0, B1, B0)
    PV_STEP(kt+5, 2, 1, B2, B1)
  }
  #undef PV_STEP

  // ---- epilogue: out = gamma*(O/lsum) + x ----
  float gmv = gamma_p[0];
  {
    int n = n0g + wn*32 + ln;
    float s = 0.f;
    #pragma unroll
    for (int j = 0; j < 8; j++) s += lsum_part[((size_t)bl*8 + j)*N_ + n];
    float f = gmv / s;
    #pragma unroll
    for (int cf = 0; cf < 2; cf++){
      #pragma unroll
      for (int rr = 0; rr < 16; rr++){
        int c = c0 + wc*64 + cf*32 + (rr & 3) + 8*(rr >> 2) + 4*h;
        size_t idx = ((size_t)b*C_ + c)*N_ + n;
        out[idx] = acc[cf][rr]*f + x[idx];
      }
    }
  }
}

extern "C" void kernel_launch(void* const* d_in, const int* in_sizes, int n_in,
                              void* d_out, int out_size, void* d_ws, size_t ws_size,
                              hipStream_t stream) {
  (void)in_sizes; (void)n_in; (void)out_size;
  const float* x  = (const float*)d_in[0];
  const float* Wq = (const float*)d_in[1];
  const float* bq = (const float*)d_in[2];
  const float* Wk = (const float*)d_in[3];
  const float* bk = (const float*)d_in[4];
  const float* Wv = (const float*)d_in[5];
  const float* bv = (const float*)d_in[6];
  const float* gm = (const float*)d_in[7];
  float* out = (float*)d_out;

  const size_t qw_b = (size_t)B_*N_*CQ*2;
  const size_t vw_b = (size_t)B_*C_*N_;            // fp8 V, 9.44 MB
  const size_t wb_b = (size_t)640*512*2;

  int nbg = 8, bsh = 3;
  for (;;){
    size_t pl_b   = (size_t)nbg*72*N_*32;          // fp8 P, pair-blocked
    size_t lsum_b = (size_t)nbg*8*N_*4;
    size_t need   = pl_b + 2*qw_b + vw_b + lsum_b + wb_b;
    if (need <= ws_size || nbg == 1) break;
    nbg >>= 1; bsh--;
  }
  size_t pl_b   = (size_t)nbg*72*N_*32;
  size_t lsum_b = (size_t)nbg*8*N_*4;

  char* wsc = (char*)d_ws;
  unsigned char* Plf = (unsigned char*)wsc;
  unsigned short* qw = (unsigned short*)(wsc + pl_b);
  unsigned short* kw = (unsigned short*)(wsc + pl_b + qw_b);
  unsigned char* vw8 = (unsigned char*)(wsc + pl_b + 2*qw_b);
  float* lsum_part   = (float*)(wsc + pl_b + 2*qw_b + vw_b);
  unsigned short* Wb = (unsigned short*)(wsc + pl_b + 2*qw_b + vw_b + lsum_b);

  k_wcvt<<<160, 256, 0, stream>>>(Wq, Wk, Wv, Wb);
  k_prep<<<576, 512, 0, stream>>>(x, bq, bk, bv, Wb, qw, kw, vw8);

  for (int b0 = 0; b0 < B_; b0 += nbg){
    k_sexp<<<144*nbg, 256, 0, stream>>>(qw, kw, Plf, lsum_part, b0, bsh);
    k_pv<<<144*nbg, 256, 0, stream>>>(vw8, Plf, lsum_part, x, gm, out, b0, bsh);
  }
}